// Round 7
// baseline (1258.931 us; speedup 1.0000x reference)
//
#include <hip/hip_runtime.h>

#define T 1024
#define BATCH 512
#define EMB 64
#define HID 64
#define NGATE 256
#define VOCABP1 50001

typedef unsigned int uint32;
typedef unsigned short ushort16;
typedef __attribute__((ext_vector_type(8))) short short8;   // 8 bf16 = 4 VGPRs
typedef __attribute__((ext_vector_type(4))) float f32x4;    // MFMA C/D

__device__ __forceinline__ float rcpf(float x) { return __builtin_amdgcn_rcpf(x); }
__device__ __forceinline__ float sigm(float x) { return rcpf(1.0f + __expf(-x)); }
__device__ __forceinline__ float tanhfast(float x) { return 1.0f - 2.0f * rcpf(__expf(2.0f * x) + 1.0f); }
__device__ __forceinline__ float bcastf(float v, int k) {
    return __int_as_float(__builtin_amdgcn_readlane(__float_as_int(v), k));
}
__device__ __forceinline__ ushort16 f2bf(float x) {        // RNE f32->bf16 (no NaN inputs)
    uint32 u = __float_as_uint(x);
    u += 0x7fffu + ((u >> 16) & 1u);
    return (ushort16)(u >> 16);
}
__device__ __forceinline__ float bf2f(ushort16 h) { return __uint_as_float(((uint32)h) << 16); }

// LDS-only barrier: drains lgkmcnt (DS visibility across waves) but leaves
// global loads in flight. __syncthreads() would emit s_waitcnt vmcnt(0)
// lgkmcnt(0) and drain the zx-gather prefetch every step (R6: ~2200 stall
// cyc/step, MfmaUtil 3.7%). Global loads have no cross-wave obligation here.
#define BARRIER_LDS() asm volatile("s_waitcnt lgkmcnt(0)\n\ts_barrier" ::: "memory")

// ---------------------------------------------------------------------------
// zx table, natural layout: ztab[v][col] = b[col] + sum_k emb[v][k]*W[k][col]
// ---------------------------------------------------------------------------
__global__ __launch_bounds__(256, 3)
void zxtab_kernel(const float* __restrict__ emb,
                  const float* __restrict__ Wf, const float* __restrict__ bf,
                  const float* __restrict__ Wb, const float* __restrict__ bb,
                  float* __restrict__ zf_tab, float* __restrict__ zb_tab)
{
    const int j = threadIdx.x;
    const int lane = j & 63;
    float wf[EMB], wb[EMB];
#pragma unroll
    for (int k = 0; k < EMB; ++k) wf[k] = Wf[k * NGATE + j];
#pragma unroll
    for (int k = 0; k < EMB; ++k) wb[k] = Wb[k * NGATE + j];
    const float bfj = bf[j];
    const float bbj = bb[j];
    for (int r = blockIdx.x; r < VOCABP1; r += gridDim.x) {
        const float ev = emb[r * EMB + lane];
        float f0 = bfj, f1 = 0.f, b0 = bbj, b1 = 0.f;
#pragma unroll
        for (int k = 0; k < EMB; k += 2) {
            const float e0 = bcastf(ev, k);
            const float e1 = bcastf(ev, k + 1);
            f0 = fmaf(e0, wf[k], f0);
            f1 = fmaf(e1, wf[k + 1], f1);
            b0 = fmaf(e0, wb[k], b0);
            b1 = fmaf(e1, wb[k + 1], b1);
        }
        zf_tab[r * NGATE + j] = f0 + f1;
        zb_tab[r * NGATE + j] = b0 + b1;
    }
}

// ---------------------------------------------------------------------------
// Step-ordered token streams: xs[d][b][s] = x[b][ d ? T-1-s : s ]
// ---------------------------------------------------------------------------
__global__ void xsprep_kernel(const int* __restrict__ x, int* __restrict__ xs)
{
    const int idx = blockIdx.x * 256 + threadIdx.x;       // 2*512*1024 total
    const int d = idx >> 19;
    const int b = (idx >> 10) & 511;
    const int s = idx & 1023;
    xs[idx] = x[b * T + (d ? (T - 1 - s) : s)];
}

// ---------------------------------------------------------------------------
// B-fragment prep: U (hi/lo bf16 split) laid out in MFMA B-frag order.
//   idx(d,w,g,ks,var,lane,j) = ((((((d*4+w)*4+g)*2+ks)*2+var)*64)+lane)*8+j
//   value = split(U[k][col]),  k = ks*32+(lane>>4)*8+j,  col = g*64+16w+(lane&15)
// ---------------------------------------------------------------------------
__global__ void bfrag_kernel(const float* __restrict__ Uf,
                             const float* __restrict__ Ub,
                             ushort16* __restrict__ bfrag)
{
    const int d = blockIdx.x;                 // 0 fwd, 1 bwd
    const float* U = d ? Ub : Uf;
    const int tid = threadIdx.x, lane = tid & 63, w = tid >> 6;
#pragma unroll
    for (int g = 0; g < 4; ++g)
#pragma unroll
    for (int ks = 0; ks < 2; ++ks)
#pragma unroll
    for (int j = 0; j < 8; ++j) {
        const int col = g * 64 + 16 * w + (lane & 15);
        const int k   = ks * 32 + (lane >> 4) * 8 + j;
        const float uv = U[k * NGATE + col];
        const ushort16 hi = f2bf(uv);
        const ushort16 lo = f2bf(uv - bf2f(hi));
        const size_t base = ((((size_t)(d * 4 + w) * 4 + g) * 2 + ks) * 2) * 512;
        bfrag[base + 0 * 512 + lane * 8 + j] = hi;
        bfrag[base + 1 * 512 + lane * 8 + j] = lo;
    }
}

// ---------------------------------------------------------------------------
// MFMA LSTM: 64 blocks (32 fwd + 32 bwd) x 256 threads; 16 sequences/block.
// Wave w owns units [16w,16w+16) for all 4 gates (tiles g=0..3).
// Per step: acc[g] = zx (C-init, f32 exact) + hi/lo-split bf16 MFMA of h@U.
// h round-trips LDS (C-layout -> A-layout). Sync is BARRIER_LDS: lgkm-only
// drain so the 1-step-ahead zx gather survives the barrier (R6's
// __syncthreads drained vmcnt(0) every step == full gather latency exposed).
// ---------------------------------------------------------------------------
__global__ __launch_bounds__(256, 1)
void lstm_mfma(const int* __restrict__ xs,
               const float* __restrict__ zf_tab,
               const float* __restrict__ zb_tab,
               const ushort16* __restrict__ bfrag,
               float* __restrict__ hcat)
{
    const int tid  = threadIdx.x;
    const int lane = tid & 63;
    const int w    = tid >> 6;          // unit group
    const int col  = lane & 15;
    const int quad = lane >> 4;
    const int d    = blockIdx.x >> 5;
    const int gb   = blockIdx.x & 31;   // batch group: batches 16gb..16gb+15

    const float* ztab = d ? zb_tab : zf_tab;
    const int ucol = 16 * w + col;              // global unit of this thread
    const int KS   = w >> 1;                    // unit>>5, wave-uniform
    const int q2   = (2 * w + (col >> 3)) & 3;  // (unit>>3)&3

    // B fragments (hi/lo): 16 x short8 — AGPR-friendly (MFMA reads natively)
    short8 Bf[4][2][2];
    {
        const ushort16* p = bfrag + ((size_t)(d * 4 + w) * 4) * 2 * 2 * 512;
#pragma unroll
        for (int g = 0; g < 4; ++g)
#pragma unroll
        for (int ks = 0; ks < 2; ++ks)
#pragma unroll
        for (int v = 0; v < 2; ++v)
            Bf[g][ks][v] = *(const short8*)&p[(((g * 2 + ks) * 2 + v) * 64 + lane) * 8];
    }

    __shared__ ushort16 A_lds[2][2][2][64][8];  // [buf][var][ks][q'*16+m][j]
    __shared__ int tokbuf[2][16];

    // zero h_{-1} fragments (both buffers)
    {
        ushort16* f = &A_lds[0][0][0][0][0];
        for (int i = tid; i < 2 * 2 * 2 * 64 * 8; i += 256) f[i] = 0;
    }
    const int* xrow_w = xs + ((size_t)(d * 512 + gb * 16 + (tid & 15))) * T;
    if (tid < 16) {
        tokbuf[0][tid] = xrow_w[0];
        tokbuf[1][tid] = xrow_w[1];
    }
    __syncthreads();    // once, outside hot loop — full drain is fine here

    int   tokc[4];
#pragma unroll
    for (int r = 0; r < 4; ++r) tokc[r] = tokbuf[0][quad * 4 + r];
    float zxC[4][4];
#pragma unroll
    for (int g = 0; g < 4; ++g)
#pragma unroll
    for (int r = 0; r < 4; ++r)
        zxC[g][r] = ztab[(size_t)tokc[r] * NGATE + g * 64 + ucol];

    float hv[4] = {0.f, 0.f, 0.f, 0.f};
    float cv[4] = {0.f, 0.f, 0.f, 0.f};

#define STEP(SV, P)                                                            \
  {                                                                            \
    BARRIER_LDS();                                                             \
    short8 Ah0 = *(const short8*)&A_lds[1 - (P)][0][0][lane][0];               \
    short8 Ah1 = *(const short8*)&A_lds[1 - (P)][0][1][lane][0];               \
    short8 Al0 = *(const short8*)&A_lds[1 - (P)][1][0][lane][0];               \
    short8 Al1 = *(const short8*)&A_lds[1 - (P)][1][1][lane][0];               \
    int tn[4];                                                                 \
    _Pragma("unroll")                                                          \
    for (int r = 0; r < 4; ++r) tn[r] = tokbuf[1 - (P)][quad * 4 + r];         \
    float zxN[4][4];                                                           \
    _Pragma("unroll")                                                          \
    for (int g = 0; g < 4; ++g)                                                \
      _Pragma("unroll")                                                        \
      for (int r = 0; r < 4; ++r)                                              \
        zxN[g][r] = ztab[(size_t)tn[r] * NGATE + g * 64 + ucol];               \
    if (tid < 16) tokbuf[(P)][tid] = ((SV) + 2 < T) ? xrow_w[(SV) + 2] : 0;    \
    f32x4 acc[4];                                                              \
    _Pragma("unroll")                                                          \
    for (int g = 0; g < 4; ++g) {                                              \
      acc[g][0] = zxC[g][0]; acc[g][1] = zxC[g][1];                            \
      acc[g][2] = zxC[g][2]; acc[g][3] = zxC[g][3];                            \
    }                                                                          \
    _Pragma("unroll")                                                          \
    for (int g = 0; g < 4; ++g) {                                              \
      acc[g] = __builtin_amdgcn_mfma_f32_16x16x32_bf16(Ah0, Bf[g][0][0], acc[g], 0, 0, 0); \
      acc[g] = __builtin_amdgcn_mfma_f32_16x16x32_bf16(Ah1, Bf[g][1][0], acc[g], 0, 0, 0); \
      acc[g] = __builtin_amdgcn_mfma_f32_16x16x32_bf16(Ah0, Bf[g][0][1], acc[g], 0, 0, 0); \
      acc[g] = __builtin_amdgcn_mfma_f32_16x16x32_bf16(Ah1, Bf[g][1][1], acc[g], 0, 0, 0); \
      acc[g] = __builtin_amdgcn_mfma_f32_16x16x32_bf16(Al0, Bf[g][0][0], acc[g], 0, 0, 0); \
      acc[g] = __builtin_amdgcn_mfma_f32_16x16x32_bf16(Al1, Bf[g][1][0], acc[g], 0, 0, 0); \
    }                                                                          \
    _Pragma("unroll")                                                          \
    for (int r = 0; r < 4; ++r) {                                              \
      const float iv = sigm(acc[0][r]);                                        \
      const float fv = sigm(acc[1][r]);                                        \
      const float gv = tanhfast(acc[2][r]);                                    \
      const float ov = sigm(acc[3][r]);                                        \
      const float cn = fmaf(fv, cv[r], iv * gv);                               \
      const float hn = ov * tanhfast(cn);                                      \
      if (tokc[r] != 0) { cv[r] = cn; hv[r] = hn; }                            \
      const ushort16 hhi = f2bf(hv[r]);                                        \
      const ushort16 hlo = f2bf(hv[r] - bf2f(hhi));                            \
      A_lds[(P)][0][KS][q2 * 16 + quad * 4 + r][col & 7] = hhi;                \
      A_lds[(P)][1][KS][q2 * 16 + quad * 4 + r][col & 7] = hlo;                \
    }                                                                          \
    _Pragma("unroll")                                                          \
    for (int r = 0; r < 4; ++r) tokc[r] = tn[r];                               \
    _Pragma("unroll")                                                          \
    for (int g = 0; g < 4; ++g)                                                \
      _Pragma("unroll")                                                        \
      for (int r = 0; r < 4; ++r) zxC[g][r] = zxN[g][r];                       \
  }

    for (int s = 0; s < T; s += 2) {
        STEP(s, 0)
        STEP(s + 1, 1)
    }
#undef STEP

#pragma unroll
    for (int r = 0; r < 4; ++r)
        hcat[(size_t)(gb * 16 + quad * 4 + r) * (2 * HID) + d * HID + ucol] = hv[r];
}

// ---------------------------------------------------------------------------
// Tiny MLP head: out[b] = relu(hcat[b] @ W1 + b1) @ W2 + b2
// ---------------------------------------------------------------------------
__global__ void mlp_kernel(const float* __restrict__ hcat,
                           const float* __restrict__ W1, const float* __restrict__ b1,
                           const float* __restrict__ W2, const float* __restrict__ b2,
                           float* __restrict__ out)
{
    const int b = blockIdx.x;
    const int tid = threadIdx.x;  // 64 threads
    __shared__ float h1[32];
    const float* h = hcat + b * (2 * HID);
    if (tid < 32) {
        float acc = b1[tid];
#pragma unroll
        for (int k = 0; k < 2 * HID; ++k) acc += h[k] * W1[k * 32 + tid];
        h1[tid] = fmaxf(acc, 0.0f);
    }
    __syncthreads();
    if (tid == 0) {
        float acc = b2[0];
#pragma unroll
        for (int m = 0; m < 32; ++m) acc += h1[m] * W2[m];
        out[b] = acc;
    }
}

extern "C" void kernel_launch(void* const* d_in, const int* in_sizes, int n_in,
                              void* d_out, int out_size, void* d_ws, size_t ws_size,
                              hipStream_t stream)
{
    const int*   x   = (const int*)d_in[0];
    const float* emb = (const float*)d_in[1];
    const float* Wf  = (const float*)d_in[2];
    const float* Uf  = (const float*)d_in[3];
    const float* bf  = (const float*)d_in[4];
    const float* Wb  = (const float*)d_in[5];
    const float* Ub  = (const float*)d_in[6];
    const float* bb  = (const float*)d_in[7];
    const float* W1  = (const float*)d_in[8];
    const float* b1  = (const float*)d_in[9];
    const float* W2  = (const float*)d_in[10];
    const float* b2  = (const float*)d_in[11];
    float* out = (float*)d_out;

    // workspace: [zf_tab | zb_tab | xs | bfrag | hcat]
    float*    zf_tab = (float*)d_ws;                              // 12800256 f32
    float*    zb_tab = zf_tab + (size_t)VOCABP1 * NGATE;          // 12800256 f32
    int*      xs     = (int*)(zb_tab + (size_t)VOCABP1 * NGATE);  // 2*512*1024 i32
    ushort16* bfrag  = (ushort16*)(xs + 2 * 512 * 1024);          // 65536 u16
    float*    hcat   = (float*)(bfrag + 65536);                   // 512*128 f32

    zxtab_kernel<<<dim3(2048), dim3(256), 0, stream>>>(
        emb, Wf, bf, Wb, bb, zf_tab, zb_tab);
    xsprep_kernel<<<dim3(2 * 512 * 1024 / 256), dim3(256), 0, stream>>>(x, xs);
    bfrag_kernel<<<dim3(2), dim3(256), 0, stream>>>(Uf, Ub, bfrag);
    lstm_mfma<<<dim3(64), dim3(256), 0, stream>>>(xs, zf_tab, zb_tab, bfrag, hcat);
    mlp_kernel<<<dim3(BATCH), dim3(64), 0, stream>>>(hcat, W1, b1, W2, b2, out);
}

// Round 8
// 895.820 us; speedup vs baseline: 1.4053x; 1.4053x over previous
//
#include <hip/hip_runtime.h>

#define T 1024
#define BATCH 512
#define EMB 64
#define HID 64
#define NGATE 256
#define VOCABP1 50001

typedef unsigned int uint32;
typedef unsigned short u16;
typedef __attribute__((ext_vector_type(8))) short short8;        // 8 bf16 = 4 VGPRs
typedef __attribute__((ext_vector_type(4))) float f32x4;         // MFMA C/D
typedef __attribute__((ext_vector_type(4))) unsigned short us4;  // 8B bf16x4

__device__ __forceinline__ float rcpf(float x) { return __builtin_amdgcn_rcpf(x); }
__device__ __forceinline__ float sigm(float x) { return rcpf(1.0f + __expf(-x)); }
__device__ __forceinline__ float tanhfast(float x) { return 1.0f - 2.0f * rcpf(__expf(2.0f * x) + 1.0f); }
__device__ __forceinline__ u16 f2bf(float x) {        // RNE f32->bf16 (no NaN inputs)
    uint32 u = __float_as_uint(x);
    u += 0x7fffu + ((u >> 16) & 1u);
    return (u16)(u >> 16);
}
__device__ __forceinline__ float bf2f(u16 h) { return __uint_as_float(((uint32)h) << 16); }

// LDS-only barrier: drains lgkmcnt (cross-wave DS visibility) but leaves
// global loads in flight across the barrier.
#define BARRIER_LDS() asm volatile("s_waitcnt lgkmcnt(0)\n\ts_barrier" ::: "memory")

// ---------------------------------------------------------------------------
// bf16 cast of the embedding table (6.4 MB -> L2/L3 resident gather target).
// ---------------------------------------------------------------------------
__global__ void embbf_kernel(const float* __restrict__ emb, u16* __restrict__ embbf)
{
    const int i = blockIdx.x * 256 + threadIdx.x;
    if (i < VOCABP1 * EMB) embbf[i] = f2bf(emb[i]);
}

// ---------------------------------------------------------------------------
// Step-ordered token streams: xs[d][b][s] = x[b][ d ? T-1-s : s ]
// ---------------------------------------------------------------------------
__global__ void xsprep_kernel(const int* __restrict__ x, int* __restrict__ xs)
{
    const int idx = blockIdx.x * 256 + threadIdx.x;       // 2*512*1024 total
    const int d = idx >> 19;
    const int b = (idx >> 10) & 511;
    const int s = idx & 1023;
    xs[idx] = x[b * T + (d ? (T - 1 - s) : s)];
}

// ---------------------------------------------------------------------------
// B-fragment prep: var 0 = U-hi, 1 = U-lo, 2 = W-hi (single bf16 for x@W).
//   idx = ((((d*4+w)*4+g)*2+ks)*3+var)*512 + lane*8 + j
//   k = ks*32+(lane>>4)*8+j,  col = g*64+16w+(lane&15)
// ---------------------------------------------------------------------------
__global__ void bfrag_kernel(const float* __restrict__ Uf, const float* __restrict__ Ub,
                             const float* __restrict__ Wf, const float* __restrict__ Wb,
                             u16* __restrict__ bfrag)
{
    const int d = blockIdx.x;                 // 0 fwd, 1 bwd
    const float* U = d ? Ub : Uf;
    const float* W = d ? Wb : Wf;
    const int tid = threadIdx.x, lane = tid & 63, w = tid >> 6;
#pragma unroll
    for (int g = 0; g < 4; ++g)
#pragma unroll
    for (int ks = 0; ks < 2; ++ks)
#pragma unroll
    for (int j = 0; j < 8; ++j) {
        const int col = g * 64 + 16 * w + (lane & 15);
        const int k   = ks * 32 + (lane >> 4) * 8 + j;
        const float uv = U[k * NGATE + col];
        const u16 uhi = f2bf(uv);
        const u16 ulo = f2bf(uv - bf2f(uhi));
        const u16 whi = f2bf(W[k * NGATE + col]);
        const size_t base = ((((size_t)(d * 4 + w) * 4 + g) * 2 + ks) * 3) * 512;
        bfrag[base + 0 * 512 + lane * 8 + j] = uhi;
        bfrag[base + 1 * 512 + lane * 8 + j] = ulo;
        bfrag[base + 2 * 512 + lane * 8 + j] = whi;
    }
}

// ---------------------------------------------------------------------------
// MFMA LSTM: 64 blocks x 256 threads; 16 sequences/block; wave w owns units
// [16w,16w+16) for all 4 gate tiles. Per step: acc[g] = bias + x@W (bf16
// MFMA from L2-resident emb gather) + h@U (hi/lo-split bf16 MFMA, ~exact).
// R7 lesson: the 51 MB f32 zx table gathered 505 MB from HBM (uncacheable),
// latency-bound at ~2590 cyc/step. Now the gather target is the 6.4 MB bf16
// emb table (L2/L3 resident, 128 B per seq-step), pipelined 2 steps deep:
// global->VGPR (1 step) -> LDS A-frag (1 step) -> MFMA.
// ---------------------------------------------------------------------------
__global__ __launch_bounds__(256, 1)
void lstm_mfma(const int* __restrict__ xs,
               const u16* __restrict__ embbf,
               const u16* __restrict__ bfragp,
               const float* __restrict__ bf, const float* __restrict__ bb,
               float* __restrict__ hcat)
{
    const int tid  = threadIdx.x;
    const int lane = tid & 63;
    const int w    = tid >> 6;          // unit group
    const int col  = lane & 15;
    const int quad = lane >> 4;
    const int d    = blockIdx.x >> 5;
    const int gb   = blockIdx.x & 31;   // batch group

    const int ucol = 16 * w + col;              // global unit of this thread
    const int KS   = w >> 1;
    const int q2   = (2 * w + (col >> 3)) & 3;

    // gather-thread role: seq mseq, 8-byte segment pseg of its emb row
    const int mseq = tid & 15;
    const int pseg = tid >> 4;                  // 0..15
    const int ks_w = pseg >> 3;
    const int qw   = (pseg >> 1) & 3;
    const int jh   = pseg & 1;

    // B fragments: U hi/lo + W hi (AGPR-friendly, MFMA reads natively)
    short8 Bf[4][2][2];
    short8 Bx[4][2];
    {
        const u16* pb = bfragp + (size_t)(d * 4 + w) * 4 * 2 * 3 * 512;
#pragma unroll
        for (int g = 0; g < 4; ++g)
#pragma unroll
        for (int ks = 0; ks < 2; ++ks) {
            Bf[g][ks][0] = *(const short8*)&pb[((g * 2 + ks) * 3 + 0) * 512 + lane * 8];
            Bf[g][ks][1] = *(const short8*)&pb[((g * 2 + ks) * 3 + 1) * 512 + lane * 8];
            Bx[g][ks]    = *(const short8*)&pb[((g * 2 + ks) * 3 + 2) * 512 + lane * 8];
        }
    }
    float biasv[4];
    {
        const float* bias = d ? bb : bf;
#pragma unroll
        for (int g = 0; g < 4; ++g) biasv[g] = bias[g * 64 + ucol];
    }

    __shared__ u16 A_lds[2][2][2][64][8];   // h frags [buf][var][ks][lane][j]
    __shared__ u16 A_ldsx[2][2][64][8];     // emb frags [buf][ks][lane][j]
    __shared__ int tokbuf[4][16];           // token ring

    {   // zero h_{-1} fragments (both buffers)
        u16* f = &A_lds[0][0][0][0][0];
        for (int i = tid; i < 2 * 2 * 2 * 64 * 8; i += 256) f[i] = 0;
    }
    const int* xrow_w = xs + ((size_t)(d * 512 + gb * 16 + mseq)) * T;
    if (tid < 16) {
        tokbuf[0][tid] = xrow_w[0];
        tokbuf[1][tid] = xrow_w[1];
        tokbuf[2][tid] = xrow_w[2];
    }
    // emb pipeline warmup: step0 tile -> LDS buf0; step1 data -> ereg[0]
    us4 ereg[2];
    {
        const us4 e0 = *(const us4*)(embbf + (size_t)xrow_w[0] * EMB + pseg * 4);
        ereg[0]      = *(const us4*)(embbf + (size_t)xrow_w[1] * EMB + pseg * 4);
        *(us4*)&A_ldsx[0][ks_w][qw * 16 + mseq][jh * 4] = e0;
    }
    __syncthreads();    // once, outside hot loop

    float hv[4] = {0.f, 0.f, 0.f, 0.f};
    float cv[4] = {0.f, 0.f, 0.f, 0.f};

#define STEP(SV, P)                                                            \
  {                                                                            \
    BARRIER_LDS();                                                             \
    short8 Ah0 = *(const short8*)&A_lds[1 - (P)][0][0][lane][0];               \
    short8 Ah1 = *(const short8*)&A_lds[1 - (P)][0][1][lane][0];               \
    short8 Al0 = *(const short8*)&A_lds[1 - (P)][1][0][lane][0];               \
    short8 Al1 = *(const short8*)&A_lds[1 - (P)][1][1][lane][0];               \
    short8 Ax0 = *(const short8*)&A_ldsx[(P)][0][lane][0];                     \
    short8 Ax1 = *(const short8*)&A_ldsx[(P)][1][lane][0];                     \
    int tokm[4];                                                               \
    _Pragma("unroll")                                                          \
    for (int r = 0; r < 4; ++r) tokm[r] = tokbuf[(SV) & 3][quad * 4 + r];      \
    const int tg = tokbuf[((SV) + 2) & 3][mseq];                               \
    if (tid < 16) tokbuf[((SV) + 3) & 3][tid] =                                \
        ((SV) + 3 < T) ? xrow_w[(SV) + 3] : 0;                                 \
    *(us4*)&A_ldsx[1 - (P)][ks_w][qw * 16 + mseq][jh * 4] = ereg[(P)];         \
    ereg[(P) ^ 1] = *(const us4*)(embbf + (size_t)tg * EMB + pseg * 4);        \
    f32x4 acc[4];                                                              \
    _Pragma("unroll")                                                          \
    for (int g = 0; g < 4; ++g) {                                              \
      acc[g][0] = biasv[g]; acc[g][1] = biasv[g];                              \
      acc[g][2] = biasv[g]; acc[g][3] = biasv[g];                              \
      acc[g] = __builtin_amdgcn_mfma_f32_16x16x32_bf16(Ax0, Bx[g][0],    acc[g], 0, 0, 0); \
      acc[g] = __builtin_amdgcn_mfma_f32_16x16x32_bf16(Ax1, Bx[g][1],    acc[g], 0, 0, 0); \
      acc[g] = __builtin_amdgcn_mfma_f32_16x16x32_bf16(Ah0, Bf[g][0][0], acc[g], 0, 0, 0); \
      acc[g] = __builtin_amdgcn_mfma_f32_16x16x32_bf16(Ah1, Bf[g][1][0], acc[g], 0, 0, 0); \
      acc[g] = __builtin_amdgcn_mfma_f32_16x16x32_bf16(Ah0, Bf[g][0][1], acc[g], 0, 0, 0); \
      acc[g] = __builtin_amdgcn_mfma_f32_16x16x32_bf16(Ah1, Bf[g][1][1], acc[g], 0, 0, 0); \
      acc[g] = __builtin_amdgcn_mfma_f32_16x16x32_bf16(Al0, Bf[g][0][0], acc[g], 0, 0, 0); \
      acc[g] = __builtin_amdgcn_mfma_f32_16x16x32_bf16(Al1, Bf[g][1][0], acc[g], 0, 0, 0); \
    }                                                                          \
    _Pragma("unroll")                                                          \
    for (int r = 0; r < 4; ++r) {                                              \
      const float iv = sigm(acc[0][r]);                                        \
      const float fv = sigm(acc[1][r]);                                        \
      const float gv = tanhfast(acc[2][r]);                                    \
      const float ov = sigm(acc[3][r]);                                        \
      const float cn = fmaf(fv, cv[r], iv * gv);                               \
      const float hn = ov * tanhfast(cn);                                      \
      if (tokm[r] != 0) { cv[r] = cn; hv[r] = hn; }                            \
      const u16 hhi = f2bf(hv[r]);                                             \
      const u16 hlo = f2bf(hv[r] - bf2f(hhi));                                 \
      A_lds[(P)][0][KS][q2 * 16 + quad * 4 + r][col & 7] = hhi;                \
      A_lds[(P)][1][KS][q2 * 16 + quad * 4 + r][col & 7] = hlo;                \
    }                                                                          \
  }

    for (int s = 0; s < T; s += 2) {
        STEP(s, 0)
        STEP(s + 1, 1)
    }
#undef STEP

#pragma unroll
    for (int r = 0; r < 4; ++r)
        hcat[(size_t)(gb * 16 + quad * 4 + r) * (2 * HID) + d * HID + ucol] = hv[r];
}

// ---------------------------------------------------------------------------
// Tiny MLP head: out[b] = relu(hcat[b] @ W1 + b1) @ W2 + b2
// ---------------------------------------------------------------------------
__global__ void mlp_kernel(const float* __restrict__ hcat,
                           const float* __restrict__ W1, const float* __restrict__ b1,
                           const float* __restrict__ W2, const float* __restrict__ b2,
                           float* __restrict__ out)
{
    const int b = blockIdx.x;
    const int tid = threadIdx.x;  // 64 threads
    __shared__ float h1[32];
    const float* h = hcat + b * (2 * HID);
    if (tid < 32) {
        float acc = b1[tid];
#pragma unroll
        for (int k = 0; k < 2 * HID; ++k) acc += h[k] * W1[k * 32 + tid];
        h1[tid] = fmaxf(acc, 0.0f);
    }
    __syncthreads();
    if (tid == 0) {
        float acc = b2[0];
#pragma unroll
        for (int m = 0; m < 32; ++m) acc += h1[m] * W2[m];
        out[b] = acc;
    }
}

extern "C" void kernel_launch(void* const* d_in, const int* in_sizes, int n_in,
                              void* d_out, int out_size, void* d_ws, size_t ws_size,
                              hipStream_t stream)
{
    const int*   x   = (const int*)d_in[0];
    const float* emb = (const float*)d_in[1];
    const float* Wf  = (const float*)d_in[2];
    const float* Uf  = (const float*)d_in[3];
    const float* bf  = (const float*)d_in[4];
    const float* Wb  = (const float*)d_in[5];
    const float* Ub  = (const float*)d_in[6];
    const float* bb  = (const float*)d_in[7];
    const float* W1  = (const float*)d_in[8];
    const float* b1  = (const float*)d_in[9];
    const float* W2  = (const float*)d_in[10];
    const float* b2  = (const float*)d_in[11];
    float* out = (float*)d_out;

    // workspace: [embbf | xs | bfrag | hcat]  (~15.3 MB)
    u16*   embbf  = (u16*)d_ws;                       // 50001*64 bf16
    int*   xs     = (int*)(embbf + 3200256);          // 2*512*1024 i32
    u16*   bfragp = (u16*)(xs + 2 * 512 * 1024);      // 98304 u16
    float* hcat   = (float*)(bfragp + 98304);         // 512*128 f32

    embbf_kernel<<<dim3((VOCABP1 * EMB + 255) / 256), dim3(256), 0, stream>>>(emb, embbf);
    xsprep_kernel<<<dim3(2 * 512 * 1024 / 256), dim3(256), 0, stream>>>(x, xs);
    bfrag_kernel<<<dim3(2), dim3(256), 0, stream>>>(Uf, Ub, Wf, Wb, bfragp);
    lstm_mfma<<<dim3(64), dim3(256), 0, stream>>>(xs, embbf, bfragp, bf, bb, hcat);
    mlp_kernel<<<dim3(BATCH), dim3(64), 0, stream>>>(hcat, W1, b1, W2, b2, out);
}